// Round 2
// baseline (420.816 us; speedup 1.0000x reference)
//
#include <hip/hip_runtime.h>

#define BINS 10
#define PAD 11           // per-thread histogram stride; gcd(11,32)=1 -> ~conflict-free
#define GRID 1024
#define BLOCK 256

// One thread per row (C=16). Each thread owns a private LDS histogram ->
// zero atomics in the hot loop (R1's 10-address LDS atomic contention was
// the 400us wall). Per-block tree reduce, partials to global, stage-2 folds.
__global__ __launch_bounds__(BLOCK) void ghm_main(const float* __restrict__ x,
                                                  const int* __restrict__ tgt,
                                                  float* __restrict__ p_sum,
                                                  unsigned int* __restrict__ p_cnt,
                                                  int n_rows) {
    __shared__ float s_sum[BLOCK * PAD];
    __shared__ unsigned int s_cnt[BLOCK * PAD];

    const int t = threadIdx.x;
    #pragma unroll
    for (int b = 0; b < BINS; ++b) { s_sum[t * PAD + b] = 0.0f; s_cnt[t * PAD + b] = 0u; }
    // no barrier needed yet: each thread touches only its own slots

    const int gid = blockIdx.x * BLOCK + t;
    const int nthreads = GRID * BLOCK;
    const float4* __restrict__ xv = (const float4*)x;

    // fp32 edges identical to jnp.arange(11)/10 (correctly-rounded k/10)
    const float edges[BINS] = {0.1f, 0.2f, 0.3f, 0.4f, 0.5f,
                               0.6f, 0.7f, 0.8f, 0.9f, 1.0f};

    for (int r = gid; r < n_rows; r += nthreads) {
        const float4 v0 = xv[(size_t)r * 4 + 0];
        const float4 v1 = xv[(size_t)r * 4 + 1];
        const float4 v2 = xv[(size_t)r * 4 + 2];
        const float4 v3 = xv[(size_t)r * 4 + 3];
        const int tg = tgt[r];

        float m = fmaxf(fmaxf(fmaxf(v0.x, v0.y), fmaxf(v0.z, v0.w)),
                        fmaxf(fmaxf(v1.x, v1.y), fmaxf(v1.z, v1.w)));
        m = fmaxf(m, fmaxf(fmaxf(fmaxf(v2.x, v2.y), fmaxf(v2.z, v2.w)),
                           fmaxf(fmaxf(v3.x, v3.y), fmaxf(v3.z, v3.w))));

        float s = expf(v0.x - m) + expf(v0.y - m) + expf(v0.z - m) + expf(v0.w - m)
                + expf(v1.x - m) + expf(v1.y - m) + expf(v1.z - m) + expf(v1.w - m)
                + expf(v2.x - m) + expf(v2.y - m) + expf(v2.z - m) + expf(v2.w - m)
                + expf(v3.x - m) + expf(v3.y - m) + expf(v3.z - m) + expf(v3.w - m);

        // select class tg (generic over 0..15; setup uses 0/1)
        const float4 vs = (tg < 8) ? ((tg < 4) ? v0 : v1) : ((tg < 12) ? v2 : v3);
        const int c = tg & 3;
        const float xt = (c < 2) ? ((c == 0) ? vs.x : vs.y) : ((c == 2) ? vs.z : vs.w);

        const float logp = xt - m - logf(s);
        const float g = fabsf(expf(logp) - (float)tg);

        int b = 0;
        #pragma unroll
        for (int k = 0; k < BINS; ++k) b += (g >= edges[k]) ? 1 : 0;
        if (b > BINS - 1) b = BINS - 1;

        s_sum[t * PAD + b] += -logp;   // private slot: plain RMW, no atomic
        s_cnt[t * PAD + b] += 1u;
    }
    __syncthreads();

    // block tree reduction over the 256 private histograms
    for (int off = BLOCK / 2; off > 0; off >>= 1) {
        if (t < off) {
            #pragma unroll
            for (int b = 0; b < BINS; ++b) {
                s_sum[t * PAD + b] += s_sum[(t + off) * PAD + b];
                s_cnt[t * PAD + b] += s_cnt[(t + off) * PAD + b];
            }
        }
        __syncthreads();
    }

    if (t < BINS) {                      // totals live at s_*[0*PAD + b] == s_*[b]
        p_sum[t * GRID + blockIdx.x] = s_sum[t];
        p_cnt[t * GRID + blockIdx.x] = s_cnt[t];
    }
}

__global__ void ghm_final(const float* __restrict__ p_sum,
                          const unsigned int* __restrict__ p_cnt,
                          float* __restrict__ out, int n_rows) {
    const int lane = threadIdx.x;  // 64 threads, 1 wave
    double total = 0.0;
    for (int b = 0; b < BINS; ++b) {
        double s = 0.0;
        unsigned long long c = 0;
        for (int k = lane; k < GRID; k += 64) {
            s += (double)p_sum[b * GRID + k];
            c += (unsigned long long)p_cnt[b * GRID + k];
        }
        #pragma unroll
        for (int off = 32; off > 0; off >>= 1) {
            s += __shfl_xor(s, off);
            c += __shfl_xor(c, off);
        }
        double cd = (double)c;
        if (cd < 1.0) cd = 1.0;
        total += s / cd;
    }
    if (lane == 0) out[0] = (float)(total * ((double)n_rows / (double)BINS));
}

extern "C" void kernel_launch(void* const* d_in, const int* in_sizes, int n_in,
                              void* d_out, int out_size, void* d_ws, size_t ws_size,
                              hipStream_t stream) {
    const float* x = (const float*)d_in[0];
    const int* tgt = (const int*)d_in[1];
    const int n_rows = in_sizes[1];  // N = 4194304

    float* p_sum = (float*)d_ws;                                // [BINS][GRID]
    unsigned int* p_cnt = (unsigned int*)((char*)d_ws + BINS * GRID * sizeof(float));

    ghm_main<<<GRID, BLOCK, 0, stream>>>(x, tgt, p_sum, p_cnt, n_rows);
    ghm_final<<<1, 64, 0, stream>>>(p_sum, p_cnt, (float*)d_out, n_rows);
}